// Round 7
// baseline (160.163 us; speedup 1.0000x reference)
//
#include <hip/hip_runtime.h>

// GraphSAGE mean aggregator on MI355X.
// out = feat@W_self + b_self + b_neigh + segment_mean(t[src], dst),  t = feat@W_neigh
// R2: CSR + gather-side reduction (no float atomics).
// R3: 3-phase parallel scan.
// R4: fused bf16-MFMA double-matmul; t stored bf16.
// R5/R6: fcvt folded into mmfused; deg from rowptr; nt hints.
// R7: gather MLP rewrite (coalesced index load + readlane broadcast, 16
//     outstanding row loads, early out-row load); mm 128-row blocks for
//     load balance; wprep fused into deg dispatch.

constexpr int N_NODES = 100000;
constexpr int N_EDGES = 640000;
constexpr int D = 128;

constexpr int SCAN_ELEMS_PER_BLOCK = 1024;
constexpr int SCAN_NBLOCKS = (N_NODES + SCAN_ELEMS_PER_BLOCK - 1) / SCAN_ELEMS_PER_BLOCK; // 98

typedef __attribute__((ext_vector_type(8))) short bf16x8;
typedef __attribute__((ext_vector_type(4))) float f32x4;
typedef __attribute__((ext_vector_type(2))) float f32x2;

__device__ __forceinline__ unsigned short f2bf(float f) {
    unsigned int u = __float_as_uint(f);
    unsigned int r = u + 0x7FFFu + ((u >> 16) & 1u);   // round-to-nearest-even
    return (unsigned short)(r >> 16);
}

// ---------------- prepass ----------------

// deg count (atomics) + weight packing fused in one dispatch (independent work).
// wp flat index i = (((m*4+ks)*4+h)*128 + c)*8 + r  holds  bf16(W_m[ks*32+h*8+r][c])
// Same (h,r)->k map as the A-fragment build in mmfused (shared k-permutation).
__global__ void deg_wprep_kernel(const int* __restrict__ dst, int* __restrict__ deg,
                                 const float* __restrict__ Ws, const float* __restrict__ Wn,
                                 unsigned short* __restrict__ wp) {
    int e = blockIdx.x * blockDim.x + threadIdx.x;
    if (e < N_EDGES) atomicAdd(&deg[dst[e]], 1);
    if (e < 2 * D * D) {
        int i = e;
        int r  = i & 7;
        int c  = (i >> 3) & 127;
        int h  = (i >> 10) & 3;
        int ks = (i >> 12) & 3;
        int m  = i >> 14;
        const float* W = m ? Wn : Ws;
        int k = ks * 32 + h * 8 + r;
        wp[i] = f2bf(W[k * D + c]);
    }
}

__global__ __launch_bounds__(256) void partial_kernel(const int* __restrict__ deg,
                                                      int* __restrict__ bsum) {
    __shared__ int wsum[4];
    const int tid = threadIdx.x;
    const int base = (blockIdx.x * 256 + tid) * 4;
    int s = 0;
    #pragma unroll
    for (int j = 0; j < 4; j++) {
        int idx = base + j;
        if (idx < N_NODES) s += deg[idx];
    }
    for (int off = 32; off > 0; off >>= 1) s += __shfl_down(s, off, 64);
    if ((tid & 63) == 0) wsum[tid >> 6] = s;
    __syncthreads();
    if (tid == 0) bsum[blockIdx.x] = wsum[0] + wsum[1] + wsum[2] + wsum[3];
}

__global__ __launch_bounds__(128) void scanb_kernel(const int* __restrict__ bsum,
                                                    int* __restrict__ boff,
                                                    int* __restrict__ rowptr) {
    __shared__ int s[128];
    const int tid = threadIdx.x;
    int v = (tid < SCAN_NBLOCKS) ? bsum[tid] : 0;
    s[tid] = v;
    __syncthreads();
    for (int off = 1; off < 128; off <<= 1) {
        int u = (tid >= off) ? s[tid - off] : 0;
        __syncthreads();
        s[tid] += u;
        __syncthreads();
    }
    if (tid < SCAN_NBLOCKS) boff[tid] = s[tid] - v;
    if (tid == 0) rowptr[N_NODES] = N_EDGES;
}

__global__ __launch_bounds__(256) void final_kernel(const int* __restrict__ deg,
                                                    const int* __restrict__ boff,
                                                    int* __restrict__ rowptr,
                                                    int* __restrict__ cursor) {
    __shared__ int wsum[4];
    const int tid = threadIdx.x;
    const int lane = tid & 63;
    const int wave = tid >> 6;
    const int base = (blockIdx.x * 256 + tid) * 4;

    int local[4];
    int tsum = 0;
    #pragma unroll
    for (int j = 0; j < 4; j++) {
        int idx = base + j;
        local[j] = (idx < N_NODES) ? deg[idx] : 0;
        tsum += local[j];
    }
    int incl = tsum;
    for (int off = 1; off < 64; off <<= 1) {
        int u = __shfl_up(incl, off, 64);
        if (lane >= off) incl += u;
    }
    if (lane == 63) wsum[wave] = incl;
    __syncthreads();
    int woff = 0;
    for (int w = 0; w < 4; w++) woff += (w < wave) ? wsum[w] : 0;

    int run = boff[blockIdx.x] + woff + (incl - tsum);
    #pragma unroll
    for (int j = 0; j < 4; j++) {
        int idx = base + j;
        if (idx < N_NODES) {
            rowptr[idx] = run;
            cursor[idx] = run;
            run += local[j];
        }
    }
}

__global__ void fill_kernel(const int* __restrict__ src, const int* __restrict__ dst,
                            int* __restrict__ cursor, int* __restrict__ csr_src) {
    int e = blockIdx.x * blockDim.x + threadIdx.x;
    if (e < N_EDGES) {
        int pos = atomicAdd(&cursor[dst[e]], 1);
        csr_src[pos] = src[e];
    }
}

// ---------------- fused double matmul (bf16 MFMA, f32 feat in) ----------------
// Block = 256 thr = 4 waves; wave owns 2 row-tiles of 16 -> block = 128 rows.
// m=0: out = feat@W_self + (b_self+b_neigh)   (f32)
// m=1: t   = feat@W_neigh                     (bf16)
__global__ __launch_bounds__(256) void mmfused_kernel(
    const float* __restrict__ feat, const unsigned short* __restrict__ wp,
    const float* __restrict__ b_self, const float* __restrict__ b_neigh,
    float* __restrict__ out, unsigned short* __restrict__ t)
{
    __shared__ unsigned short lw[2 * 4 * 4 * 128 * 8];   // 64 KB packed fragments

    const int tid = threadIdx.x;
    {   // stage packed weights linearly
        const uint4* s = (const uint4*)wp;
        uint4* d = (uint4*)lw;
        #pragma unroll
        for (int i = 0; i < 16; i++) d[tid + i * 256] = s[tid + i * 256];
    }
    __syncthreads();

    const int wave = tid >> 6, lane = tid & 63;
    const int h = lane >> 4, c = lane & 15;
    const int row_base = blockIdx.x * 128 + wave * 32;

    // A fragments from f32 feat, converted in-register:
    // a[ti][ks] = bf16(feat[row_base+ti*16+c][ks*32+h*8 .. +8))
    bf16x8 a[2][4];
    #pragma unroll
    for (int ti = 0; ti < 2; ti++) {
        int row = row_base + ti * 16 + c;
        int rowc = min(row, N_NODES - 1);             // clamp; stores are guarded
        const float4* fr = (const float4*)(feat + (size_t)rowc * D);
        #pragma unroll
        for (int ks = 0; ks < 4; ks++) {
            float4 u = fr[ks * 8 + h * 2];
            float4 v = fr[ks * 8 + h * 2 + 1];
            bf16x8 f;
            f[0] = (short)f2bf(u.x); f[1] = (short)f2bf(u.y);
            f[2] = (short)f2bf(u.z); f[3] = (short)f2bf(u.w);
            f[4] = (short)f2bf(v.x); f[5] = (short)f2bf(v.y);
            f[6] = (short)f2bf(v.z); f[7] = (short)f2bf(v.w);
            a[ti][ks] = f;
        }
    }

    #pragma unroll
    for (int m = 0; m < 2; m++) {
        for (int ct = 0; ct < 8; ct++) {
            bf16x8 b[4];
            #pragma unroll
            for (int ks = 0; ks < 4; ks++)
                b[ks] = ((const bf16x8*)lw)[((m * 4 + ks) * 4 + h) * 128 + ct * 16 + c];

            f32x4 acc[2];
            #pragma unroll
            for (int ti = 0; ti < 2; ti++) acc[ti] = f32x4{0.f, 0.f, 0.f, 0.f};
            #pragma unroll
            for (int ks = 0; ks < 4; ks++)
                #pragma unroll
                for (int ti = 0; ti < 2; ti++)
                    acc[ti] = __builtin_amdgcn_mfma_f32_16x16x32_bf16(a[ti][ks], b[ks], acc[ti], 0, 0, 0);

            const int col = ct * 16 + c;
            if (m == 0) {
                const float bias = b_self[col] + b_neigh[col];
                #pragma unroll
                for (int ti = 0; ti < 2; ti++) {
                    if (row_base + ti * 16 < N_NODES) {   // N%16==0: tile guard exact
                        #pragma unroll
                        for (int q = 0; q < 4; q++) {
                            int row = row_base + ti * 16 + h * 4 + q;   // C/D: row=(lane>>4)*4+reg
                            out[(size_t)row * D + col] = acc[ti][q] + bias;
                        }
                    }
                }
            } else {
                #pragma unroll
                for (int ti = 0; ti < 2; ti++) {
                    if (row_base + ti * 16 < N_NODES) {
                        #pragma unroll
                        for (int q = 0; q < 4; q++) {
                            int row = row_base + ti * 16 + h * 4 + q;
                            t[(size_t)row * D + col] = f2bf(acc[ti][q]);
                        }
                    }
                }
            }
        }
    }
}

// ---------------- gather (readlane index broadcast, 16-deep MLP) ----------------
__global__ __launch_bounds__(256) void gather_kernel(
    const unsigned short* __restrict__ t, const int* __restrict__ csr_src,
    const int* __restrict__ rowptr, float* __restrict__ out)
{
    const int lane = threadIdx.x & 63;
    const int n = (blockIdx.x * blockDim.x + threadIdx.x) >> 6;
    if (n >= N_NODES) return;

    const int e0 = rowptr[n];
    const int e1 = rowptr[n + 1];

    // out-row load is independent of the edge list: issue it first.
    f32x2* orow = (f32x2*)(out + (size_t)n * D) + lane;
    f32x2 o = __builtin_nontemporal_load(orow);

    float ax = 0.f, ay = 0.f;
    for (int base = e0; base < e1; base += 16) {
        const int cnt = min(16, e1 - base);          // wave-uniform
        int myidx = (lane < cnt) ? csr_src[base + lane] : 0;   // one coalesced load
        unsigned int vv[16];
        #pragma unroll
        for (int j = 0; j < 16; j++) {
            if (j < cnt) {
                int s = __builtin_amdgcn_readlane(myidx, j);   // SGPR base
                vv[j] = ((const unsigned int*)(t + (size_t)s * D))[lane];
            }
        }
        #pragma unroll
        for (int j = 0; j < 16; j++) {
            if (j < cnt) {
                ax += __uint_as_float(vv[j] << 16);
                ay += __uint_as_float(vv[j] & 0xFFFF0000u);
            }
        }
    }
    const float sc = 1.0f / (float)max(e1 - e0, 1);
    o.x += ax * sc;
    o.y += ay * sc;
    __builtin_nontemporal_store(o, orow);
}

extern "C" void kernel_launch(void* const* d_in, const int* in_sizes, int n_in,
                              void* d_out, int out_size, void* d_ws, size_t ws_size,
                              hipStream_t stream) {
    const float* feat    = (const float*)d_in[0];
    const int*   src     = (const int*)d_in[1];
    const int*   dst     = (const int*)d_in[2];
    const float* W_self  = (const float*)d_in[3];
    const float* b_self  = (const float*)d_in[4];
    const float* W_neigh = (const float*)d_in[5];
    const float* b_neigh = (const float*)d_in[6];
    float* out = (float*)d_out;

    // ws layout: t [N*D bf16] | wp [2*D*D bf16] | deg [N] | rowptr [N+1] |
    //            cursor [N] | csr_src [E] | bsum | boff
    unsigned short* t  = (unsigned short*)d_ws;
    unsigned short* wp = t + (size_t)N_NODES * D;
    int*   deg     = (int*)(wp + 2 * D * D);
    int*   rowptr  = deg + N_NODES;
    int*   cursor  = rowptr + (N_NODES + 1);
    int*   csr_src = cursor + N_NODES;
    int*   bsum    = csr_src + N_EDGES;
    int*   boff    = bsum + SCAN_NBLOCKS;

    (void)hipMemsetAsync(deg, 0, N_NODES * sizeof(int), stream);
    deg_wprep_kernel<<<(N_EDGES + 255) / 256, 256, 0, stream>>>(dst, deg, W_self, W_neigh, wp);

    partial_kernel<<<SCAN_NBLOCKS, 256, 0, stream>>>(deg, bsum);
    scanb_kernel<<<1, 128, 0, stream>>>(bsum, boff, rowptr);
    final_kernel<<<SCAN_NBLOCKS, 256, 0, stream>>>(deg, boff, rowptr, cursor);

    fill_kernel<<<(N_EDGES + 255) / 256, 256, 0, stream>>>(src, dst, cursor, csr_src);

    mmfused_kernel<<<(N_NODES + 127) / 128, 256, 0, stream>>>(feat, wp, b_self, b_neigh, out, t);

    gather_kernel<<<25000, 256, 0, stream>>>(t, csr_src, rowptr, out);
}

// Round 8
// 158.006 us; speedup vs baseline: 1.0137x; 1.0137x over previous
//
#include <hip/hip_runtime.h>

// GraphSAGE mean aggregator on MI355X.
// out = feat@W_self + b_self + b_neigh + segment_mean(t[src], dst),  t = feat@W_neigh
// R2: CSR + gather-side reduction.  R3: parallel scan.  R4: fused bf16-MFMA
// double-matmul, t bf16.  R5/R6: fcvt folded in, nt hints.  R7: 128-row mm blocks.
// R8: gather = branch-free predicated 8-batches (no serial tail, 8-deep MLP);
//     CSR build fused into ONE kernel (98 co-resident blocks + atomic grid bars).

constexpr int N_NODES = 100000;
constexpr int N_EDGES = 640000;
constexpr int D = 128;

constexpr int CSR_NBLOCKS = 98;                 // 98 x 1024 elems covers 100000
constexpr int CSR_THREADS = 256;

typedef __attribute__((ext_vector_type(8))) short bf16x8;
typedef __attribute__((ext_vector_type(4))) float f32x4;
typedef __attribute__((ext_vector_type(2))) float f32x2;

__device__ __forceinline__ unsigned short f2bf(float f) {
    unsigned int u = __float_as_uint(f);
    unsigned int r = u + 0x7FFFu + ((u >> 16) & 1u);   // round-to-nearest-even
    return (unsigned short)(r >> 16);
}

// ---------------- prepass: deg count + weight packing (independent work) -----
// wp flat index i = (((m*4+ks)*4+h)*128 + c)*8 + r  holds  bf16(W_m[ks*32+h*8+r][c])
// Same (h,r)->k map as the A-fragment build in mmfused (shared k-permutation).
__global__ void deg_wprep_kernel(const int* __restrict__ dst, int* __restrict__ deg,
                                 const float* __restrict__ Ws, const float* __restrict__ Wn,
                                 unsigned short* __restrict__ wp) {
    int e = blockIdx.x * blockDim.x + threadIdx.x;
    if (e < N_EDGES) atomicAdd(&deg[dst[e]], 1);
    if (e < 2 * D * D) {
        int i = e;
        int r  = i & 7;
        int c  = (i >> 3) & 127;
        int h  = (i >> 10) & 3;
        int ks = (i >> 12) & 3;
        int m  = i >> 14;
        const float* W = m ? Wn : Ws;
        int k = ks * 32 + h * 8 + r;
        wp[i] = f2bf(W[k * D + c]);
    }
}

// ---------------- fused CSR build: scan + fill in one dispatch ----------------
// 98 blocks x 256 thr, all co-resident (<< 256 CUs) -> atomic-counter grid
// barriers are safe. ctr[0..1] zeroed by memsetAsync before this launch.
__device__ __forceinline__ void grid_barrier(int* ctr) {
    __syncthreads();
    if (threadIdx.x == 0) {
        __threadfence();   // release this block's prior writes (device scope)
        __hip_atomic_fetch_add(ctr, 1, __ATOMIC_ACQ_REL, __HIP_MEMORY_SCOPE_AGENT);
        while (__hip_atomic_load(ctr, __ATOMIC_ACQUIRE, __HIP_MEMORY_SCOPE_AGENT)
               < CSR_NBLOCKS) {}
    }
    __syncthreads();
}

__global__ __launch_bounds__(CSR_THREADS) void csr_kernel(
    const int* __restrict__ deg, const int* __restrict__ src,
    const int* __restrict__ dst, int* __restrict__ rowptr,
    int* __restrict__ cursor, int* __restrict__ csr_src,
    int* __restrict__ bsum, int* __restrict__ ctr)
{
    __shared__ int wsum[4];
    const int tid = threadIdx.x;
    const int lane = tid & 63;
    const int wave = tid >> 6;
    const int base = (blockIdx.x * CSR_THREADS + tid) * 4;

    // Phase 1: per-block sum of deg over this block's 1024 elements.
    int local[4];
    int tsum = 0;
    #pragma unroll
    for (int j = 0; j < 4; j++) {
        int idx = base + j;
        local[j] = (idx < N_NODES) ? deg[idx] : 0;
        tsum += local[j];
    }
    {
        int s = tsum;
        for (int off = 32; off > 0; off >>= 1) s += __shfl_down(s, off, 64);
        if (lane == 0) wsum[wave] = s;
        __syncthreads();
        if (tid == 0) bsum[blockIdx.x] = wsum[0] + wsum[1] + wsum[2] + wsum[3];
    }

    grid_barrier(&ctr[0]);                       // all bsum[] published

    // Phase 2: each block computes its own exclusive block offset (redundantly),
    // then intra-block scan -> rowptr, cursor.
    int v = (tid < blockIdx.x) ? bsum[tid] : 0;  // CSR_NBLOCKS <= 256
    for (int off = 32; off > 0; off >>= 1) v += __shfl_down(v, off, 64);
    __syncthreads();                             // wsum reuse
    if (lane == 0) wsum[wave] = v;
    __syncthreads();
    const int boff = wsum[0] + wsum[1] + wsum[2] + wsum[3];

    int incl = tsum;
    for (int off = 1; off < 64; off <<= 1) {
        int u = __shfl_up(incl, off, 64);
        if (lane >= off) incl += u;
    }
    __syncthreads();
    if (lane == 63) wsum[wave] = incl;
    __syncthreads();
    int woff = 0;
    for (int w = 0; w < 4; w++) woff += (w < wave) ? wsum[w] : 0;

    int run = boff + woff + (incl - tsum);
    #pragma unroll
    for (int j = 0; j < 4; j++) {
        int idx = base + j;
        if (idx < N_NODES) {
            rowptr[idx] = run;
            cursor[idx] = run;
            run += local[j];
        }
    }
    if (blockIdx.x == 0 && tid == 0) rowptr[N_NODES] = N_EDGES;

    grid_barrier(&ctr[1]);                       // all cursor[] ready

    // Phase 3: counting-sort fill, grid-stride over edges.
    for (int e = blockIdx.x * CSR_THREADS + tid; e < N_EDGES;
         e += CSR_NBLOCKS * CSR_THREADS) {
        int pos = atomicAdd(&cursor[dst[e]], 1);
        csr_src[pos] = src[e];
    }
}

// ---------------- fused double matmul (bf16 MFMA, f32 feat in) ----------------
// Block = 256 thr = 4 waves; wave owns 2 row-tiles of 16 -> block = 128 rows.
__global__ __launch_bounds__(256) void mmfused_kernel(
    const float* __restrict__ feat, const unsigned short* __restrict__ wp,
    const float* __restrict__ b_self, const float* __restrict__ b_neigh,
    float* __restrict__ out, unsigned short* __restrict__ t)
{
    __shared__ unsigned short lw[2 * 4 * 4 * 128 * 8];   // 64 KB packed fragments

    const int tid = threadIdx.x;
    {
        const uint4* s = (const uint4*)wp;
        uint4* d = (uint4*)lw;
        #pragma unroll
        for (int i = 0; i < 16; i++) d[tid + i * 256] = s[tid + i * 256];
    }
    __syncthreads();

    const int wave = tid >> 6, lane = tid & 63;
    const int h = lane >> 4, c = lane & 15;
    const int row_base = blockIdx.x * 128 + wave * 32;

    bf16x8 a[2][4];
    #pragma unroll
    for (int ti = 0; ti < 2; ti++) {
        int row = row_base + ti * 16 + c;
        int rowc = min(row, N_NODES - 1);             // clamp; stores are guarded
        const float4* fr = (const float4*)(feat + (size_t)rowc * D);
        #pragma unroll
        for (int ks = 0; ks < 4; ks++) {
            float4 u = fr[ks * 8 + h * 2];
            float4 v = fr[ks * 8 + h * 2 + 1];
            bf16x8 f;
            f[0] = (short)f2bf(u.x); f[1] = (short)f2bf(u.y);
            f[2] = (short)f2bf(u.z); f[3] = (short)f2bf(u.w);
            f[4] = (short)f2bf(v.x); f[5] = (short)f2bf(v.y);
            f[6] = (short)f2bf(v.z); f[7] = (short)f2bf(v.w);
            a[ti][ks] = f;
        }
    }

    #pragma unroll
    for (int m = 0; m < 2; m++) {
        for (int ct = 0; ct < 8; ct++) {
            bf16x8 b[4];
            #pragma unroll
            for (int ks = 0; ks < 4; ks++)
                b[ks] = ((const bf16x8*)lw)[((m * 4 + ks) * 4 + h) * 128 + ct * 16 + c];

            f32x4 acc[2];
            #pragma unroll
            for (int ti = 0; ti < 2; ti++) acc[ti] = f32x4{0.f, 0.f, 0.f, 0.f};
            #pragma unroll
            for (int ks = 0; ks < 4; ks++)
                #pragma unroll
                for (int ti = 0; ti < 2; ti++)
                    acc[ti] = __builtin_amdgcn_mfma_f32_16x16x32_bf16(a[ti][ks], b[ks], acc[ti], 0, 0, 0);

            const int col = ct * 16 + c;
            if (m == 0) {
                const float bias = b_self[col] + b_neigh[col];
                #pragma unroll
                for (int ti = 0; ti < 2; ti++) {
                    if (row_base + ti * 16 < N_NODES) {
                        #pragma unroll
                        for (int q = 0; q < 4; q++) {
                            int row = row_base + ti * 16 + h * 4 + q;   // C/D: row=(lane>>4)*4+reg
                            out[(size_t)row * D + col] = acc[ti][q] + bias;
                        }
                    }
                }
            } else {
                #pragma unroll
                for (int ti = 0; ti < 2; ti++) {
                    if (row_base + ti * 16 < N_NODES) {
                        #pragma unroll
                        for (int q = 0; q < 4; q++) {
                            int row = row_base + ti * 16 + h * 4 + q;
                            t[(size_t)row * D + col] = f2bf(acc[ti][q]);
                        }
                    }
                }
            }
        }
    }
}

// ---------------- gather: branch-free predicated 8-batches ----------------
// One wave per node. Per batch: 8 clamped index loads + 8 row loads all in
// flight (duplicates of last edge hit L1), accumulate masked by 0/1 weight.
__global__ __launch_bounds__(256) void gather_kernel(
    const unsigned short* __restrict__ t, const int* __restrict__ csr_src,
    const int* __restrict__ rowptr, float* __restrict__ out)
{
    const int lane = threadIdx.x & 63;
    const int n = (blockIdx.x * blockDim.x + threadIdx.x) >> 6;
    if (n >= N_NODES) return;

    const int e0 = rowptr[n];
    const int e1 = rowptr[n + 1];

    // independent of edge list: issue early
    f32x2* orow = (f32x2*)(out + (size_t)n * D) + lane;
    f32x2 o = __builtin_nontemporal_load(orow);

    float ax = 0.f, ay = 0.f;
    for (int base = e0; base < e1; base += 8) {
        int sidx[8];
        #pragma unroll
        for (int j = 0; j < 8; j++) {
            int ee = base + j;
            ee = (ee < e1) ? ee : (e1 - 1);          // clamp, no branch
            sidx[j] = csr_src[ee];
        }
        unsigned int v[8];
        #pragma unroll
        for (int j = 0; j < 8; j++)
            v[j] = ((const unsigned int*)(t + (size_t)sidx[j] * D))[lane];
        #pragma unroll
        for (int j = 0; j < 8; j++) {
            const float w = (base + j < e1) ? 1.0f : 0.0f;
            ax = fmaf(w, __uint_as_float(v[j] << 16), ax);
            ay = fmaf(w, __uint_as_float(v[j] & 0xFFFF0000u), ay);
        }
    }
    const float sc = 1.0f / (float)max(e1 - e0, 1);
    o.x += ax * sc;
    o.y += ay * sc;
    __builtin_nontemporal_store(o, orow);
}

extern "C" void kernel_launch(void* const* d_in, const int* in_sizes, int n_in,
                              void* d_out, int out_size, void* d_ws, size_t ws_size,
                              hipStream_t stream) {
    const float* feat    = (const float*)d_in[0];
    const int*   src     = (const int*)d_in[1];
    const int*   dst     = (const int*)d_in[2];
    const float* W_self  = (const float*)d_in[3];
    const float* b_self  = (const float*)d_in[4];
    const float* W_neigh = (const float*)d_in[5];
    const float* b_neigh = (const float*)d_in[6];
    float* out = (float*)d_out;

    // ws layout: t [N*D bf16] | wp [2*D*D bf16] | deg [N] | rowptr [N+1] |
    //            cursor [N] | csr_src [E] | bsum [98] | ctr [2]
    unsigned short* t  = (unsigned short*)d_ws;
    unsigned short* wp = t + (size_t)N_NODES * D;
    int*   deg     = (int*)(wp + 2 * D * D);
    int*   rowptr  = deg + N_NODES;
    int*   cursor  = rowptr + (N_NODES + 1);
    int*   csr_src = cursor + N_NODES;
    int*   bsum    = csr_src + N_EDGES;
    int*   ctr     = bsum + CSR_NBLOCKS;

    (void)hipMemsetAsync(deg, 0, N_NODES * sizeof(int), stream);
    (void)hipMemsetAsync(ctr, 0, 2 * sizeof(int), stream);

    deg_wprep_kernel<<<(N_EDGES + 255) / 256, 256, 0, stream>>>(dst, deg, W_self, W_neigh, wp);

    csr_kernel<<<CSR_NBLOCKS, CSR_THREADS, 0, stream>>>(deg, src, dst, rowptr,
                                                        cursor, csr_src, bsum, ctr);

    mmfused_kernel<<<(N_NODES + 127) / 128, 256, 0, stream>>>(feat, wp, b_self, b_neigh, out, t);

    gather_kernel<<<25000, 256, 0, stream>>>(t, csr_src, rowptr, out);
}

// Round 9
// 147.910 us; speedup vs baseline: 1.0828x; 1.0683x over previous
//
#include <hip/hip_runtime.h>

// GraphSAGE mean aggregator on MI355X.
// out = feat@W_self + b_self + b_neigh + segment_mean(t[src], dst),  t = feat@W_neigh
// R2: CSR + gather-side reduction.  R3: parallel scan.  R4: fused bf16-MFMA
// double-matmul, t bf16.  R5/R6: fcvt folded in, nt hints.  R7: 128-row mm blocks.
// R8: gather = branch-free predicated 8-batches (kept — it won).
// R9: revert CSR fusion (98-block grid-barrier kernel serialized the 640K-edge
//     fill: 25 dependent atomic chains/thread, 3.7% occupancy, 50us). Back to
//     4 natural-width kernels.

constexpr int N_NODES = 100000;
constexpr int N_EDGES = 640000;
constexpr int D = 128;

constexpr int SCAN_ELEMS_PER_BLOCK = 1024;   // 256 threads x 4
constexpr int SCAN_NBLOCKS = (N_NODES + SCAN_ELEMS_PER_BLOCK - 1) / SCAN_ELEMS_PER_BLOCK; // 98

typedef __attribute__((ext_vector_type(8))) short bf16x8;
typedef __attribute__((ext_vector_type(4))) float f32x4;
typedef __attribute__((ext_vector_type(2))) float f32x2;

__device__ __forceinline__ unsigned short f2bf(float f) {
    unsigned int u = __float_as_uint(f);
    unsigned int r = u + 0x7FFFu + ((u >> 16) & 1u);   // round-to-nearest-even
    return (unsigned short)(r >> 16);
}

// ---------------- prepass: deg count + weight packing (independent work) -----
// wp flat index i = (((m*4+ks)*4+h)*128 + c)*8 + r  holds  bf16(W_m[ks*32+h*8+r][c])
// Same (h,r)->k map as the A-fragment build in mmfused (shared k-permutation).
__global__ void deg_wprep_kernel(const int* __restrict__ dst, int* __restrict__ deg,
                                 const float* __restrict__ Ws, const float* __restrict__ Wn,
                                 unsigned short* __restrict__ wp) {
    int e = blockIdx.x * blockDim.x + threadIdx.x;
    if (e < N_EDGES) atomicAdd(&deg[dst[e]], 1);
    if (e < 2 * D * D) {
        int i = e;
        int r  = i & 7;
        int c  = (i >> 3) & 127;
        int h  = (i >> 10) & 3;
        int ks = (i >> 12) & 3;
        int m  = i >> 14;
        const float* W = m ? Wn : Ws;
        int k = ks * 32 + h * 8 + r;
        wp[i] = f2bf(W[k * D + c]);
    }
}

// ---------------- 3-phase scan + fill (natural widths) ----------------

__global__ __launch_bounds__(256) void partial_kernel(const int* __restrict__ deg,
                                                      int* __restrict__ bsum) {
    __shared__ int wsum[4];
    const int tid = threadIdx.x;
    const int base = (blockIdx.x * 256 + tid) * 4;
    int s = 0;
    #pragma unroll
    for (int j = 0; j < 4; j++) {
        int idx = base + j;
        if (idx < N_NODES) s += deg[idx];
    }
    for (int off = 32; off > 0; off >>= 1) s += __shfl_down(s, off, 64);
    if ((tid & 63) == 0) wsum[tid >> 6] = s;
    __syncthreads();
    if (tid == 0) bsum[blockIdx.x] = wsum[0] + wsum[1] + wsum[2] + wsum[3];
}

__global__ __launch_bounds__(128) void scanb_kernel(const int* __restrict__ bsum,
                                                    int* __restrict__ boff,
                                                    int* __restrict__ rowptr) {
    __shared__ int s[128];
    const int tid = threadIdx.x;
    int v = (tid < SCAN_NBLOCKS) ? bsum[tid] : 0;
    s[tid] = v;
    __syncthreads();
    for (int off = 1; off < 128; off <<= 1) {
        int u = (tid >= off) ? s[tid - off] : 0;
        __syncthreads();
        s[tid] += u;
        __syncthreads();
    }
    if (tid < SCAN_NBLOCKS) boff[tid] = s[tid] - v;
    if (tid == 0) rowptr[N_NODES] = N_EDGES;
}

__global__ __launch_bounds__(256) void final_kernel(const int* __restrict__ deg,
                                                    const int* __restrict__ boff,
                                                    int* __restrict__ rowptr,
                                                    int* __restrict__ cursor) {
    __shared__ int wsum[4];
    const int tid = threadIdx.x;
    const int lane = tid & 63;
    const int wave = tid >> 6;
    const int base = (blockIdx.x * 256 + tid) * 4;

    int local[4];
    int tsum = 0;
    #pragma unroll
    for (int j = 0; j < 4; j++) {
        int idx = base + j;
        local[j] = (idx < N_NODES) ? deg[idx] : 0;
        tsum += local[j];
    }
    int incl = tsum;
    for (int off = 1; off < 64; off <<= 1) {
        int u = __shfl_up(incl, off, 64);
        if (lane >= off) incl += u;
    }
    if (lane == 63) wsum[wave] = incl;
    __syncthreads();
    int woff = 0;
    for (int w = 0; w < 4; w++) woff += (w < wave) ? wsum[w] : 0;

    int run = boff[blockIdx.x] + woff + (incl - tsum);
    #pragma unroll
    for (int j = 0; j < 4; j++) {
        int idx = base + j;
        if (idx < N_NODES) {
            rowptr[idx] = run;
            cursor[idx] = run;
            run += local[j];
        }
    }
}

__global__ void fill_kernel(const int* __restrict__ src, const int* __restrict__ dst,
                            int* __restrict__ cursor, int* __restrict__ csr_src) {
    int e = blockIdx.x * blockDim.x + threadIdx.x;
    if (e < N_EDGES) {
        int pos = atomicAdd(&cursor[dst[e]], 1);
        csr_src[pos] = src[e];
    }
}

// ---------------- fused double matmul (bf16 MFMA, f32 feat in) ----------------
// Block = 256 thr = 4 waves; wave owns 2 row-tiles of 16 -> block = 128 rows.
__global__ __launch_bounds__(256) void mmfused_kernel(
    const float* __restrict__ feat, const unsigned short* __restrict__ wp,
    const float* __restrict__ b_self, const float* __restrict__ b_neigh,
    float* __restrict__ out, unsigned short* __restrict__ t)
{
    __shared__ unsigned short lw[2 * 4 * 4 * 128 * 8];   // 64 KB packed fragments

    const int tid = threadIdx.x;
    {
        const uint4* s = (const uint4*)wp;
        uint4* d = (uint4*)lw;
        #pragma unroll
        for (int i = 0; i < 16; i++) d[tid + i * 256] = s[tid + i * 256];
    }
    __syncthreads();

    const int wave = tid >> 6, lane = tid & 63;
    const int h = lane >> 4, c = lane & 15;
    const int row_base = blockIdx.x * 128 + wave * 32;

    bf16x8 a[2][4];
    #pragma unroll
    for (int ti = 0; ti < 2; ti++) {
        int row = row_base + ti * 16 + c;
        int rowc = min(row, N_NODES - 1);             // clamp; stores are guarded
        const float4* fr = (const float4*)(feat + (size_t)rowc * D);
        #pragma unroll
        for (int ks = 0; ks < 4; ks++) {
            float4 u = fr[ks * 8 + h * 2];
            float4 v = fr[ks * 8 + h * 2 + 1];
            bf16x8 f;
            f[0] = (short)f2bf(u.x); f[1] = (short)f2bf(u.y);
            f[2] = (short)f2bf(u.z); f[3] = (short)f2bf(u.w);
            f[4] = (short)f2bf(v.x); f[5] = (short)f2bf(v.y);
            f[6] = (short)f2bf(v.z); f[7] = (short)f2bf(v.w);
            a[ti][ks] = f;
        }
    }

    #pragma unroll
    for (int m = 0; m < 2; m++) {
        for (int ct = 0; ct < 8; ct++) {
            bf16x8 b[4];
            #pragma unroll
            for (int ks = 0; ks < 4; ks++)
                b[ks] = ((const bf16x8*)lw)[((m * 4 + ks) * 4 + h) * 128 + ct * 16 + c];

            f32x4 acc[2];
            #pragma unroll
            for (int ti = 0; ti < 2; ti++) acc[ti] = f32x4{0.f, 0.f, 0.f, 0.f};
            #pragma unroll
            for (int ks = 0; ks < 4; ks++)
                #pragma unroll
                for (int ti = 0; ti < 2; ti++)
                    acc[ti] = __builtin_amdgcn_mfma_f32_16x16x32_bf16(a[ti][ks], b[ks], acc[ti], 0, 0, 0);

            const int col = ct * 16 + c;
            if (m == 0) {
                const float bias = b_self[col] + b_neigh[col];
                #pragma unroll
                for (int ti = 0; ti < 2; ti++) {
                    if (row_base + ti * 16 < N_NODES) {
                        #pragma unroll
                        for (int q = 0; q < 4; q++) {
                            int row = row_base + ti * 16 + h * 4 + q;   // C/D: row=(lane>>4)*4+reg
                            out[(size_t)row * D + col] = acc[ti][q] + bias;
                        }
                    }
                }
            } else {
                #pragma unroll
                for (int ti = 0; ti < 2; ti++) {
                    if (row_base + ti * 16 < N_NODES) {
                        #pragma unroll
                        for (int q = 0; q < 4; q++) {
                            int row = row_base + ti * 16 + h * 4 + q;
                            t[(size_t)row * D + col] = f2bf(acc[ti][q]);
                        }
                    }
                }
            }
        }
    }
}

// ---------------- gather: branch-free predicated 8-batches ----------------
__global__ __launch_bounds__(256) void gather_kernel(
    const unsigned short* __restrict__ t, const int* __restrict__ csr_src,
    const int* __restrict__ rowptr, float* __restrict__ out)
{
    const int lane = threadIdx.x & 63;
    const int n = (blockIdx.x * blockDim.x + threadIdx.x) >> 6;
    if (n >= N_NODES) return;

    const int e0 = rowptr[n];
    const int e1 = rowptr[n + 1];

    // independent of edge list: issue early
    f32x2* orow = (f32x2*)(out + (size_t)n * D) + lane;
    f32x2 o = __builtin_nontemporal_load(orow);

    float ax = 0.f, ay = 0.f;
    for (int base = e0; base < e1; base += 8) {
        int sidx[8];
        #pragma unroll
        for (int j = 0; j < 8; j++) {
            int ee = base + j;
            ee = (ee < e1) ? ee : (e1 - 1);          // clamp, no branch
            sidx[j] = csr_src[ee];
        }
        unsigned int v[8];
        #pragma unroll
        for (int j = 0; j < 8; j++)
            v[j] = ((const unsigned int*)(t + (size_t)sidx[j] * D))[lane];
        #pragma unroll
        for (int j = 0; j < 8; j++) {
            const float w = (base + j < e1) ? 1.0f : 0.0f;
            ax = fmaf(w, __uint_as_float(v[j] << 16), ax);
            ay = fmaf(w, __uint_as_float(v[j] & 0xFFFF0000u), ay);
        }
    }
    const float sc = 1.0f / (float)max(e1 - e0, 1);
    o.x += ax * sc;
    o.y += ay * sc;
    __builtin_nontemporal_store(o, orow);
}

extern "C" void kernel_launch(void* const* d_in, const int* in_sizes, int n_in,
                              void* d_out, int out_size, void* d_ws, size_t ws_size,
                              hipStream_t stream) {
    const float* feat    = (const float*)d_in[0];
    const int*   src     = (const int*)d_in[1];
    const int*   dst     = (const int*)d_in[2];
    const float* W_self  = (const float*)d_in[3];
    const float* b_self  = (const float*)d_in[4];
    const float* W_neigh = (const float*)d_in[5];
    const float* b_neigh = (const float*)d_in[6];
    float* out = (float*)d_out;

    // ws layout: t [N*D bf16] | wp [2*D*D bf16] | deg [N] | rowptr [N+1] |
    //            cursor [N] | csr_src [E] | bsum [98] | boff [98]
    unsigned short* t  = (unsigned short*)d_ws;
    unsigned short* wp = t + (size_t)N_NODES * D;
    int*   deg     = (int*)(wp + 2 * D * D);
    int*   rowptr  = deg + N_NODES;
    int*   cursor  = rowptr + (N_NODES + 1);
    int*   csr_src = cursor + N_NODES;
    int*   bsum    = csr_src + N_EDGES;
    int*   boff    = bsum + SCAN_NBLOCKS;

    (void)hipMemsetAsync(deg, 0, N_NODES * sizeof(int), stream);

    deg_wprep_kernel<<<(N_EDGES + 255) / 256, 256, 0, stream>>>(dst, deg, W_self, W_neigh, wp);

    partial_kernel<<<SCAN_NBLOCKS, 256, 0, stream>>>(deg, bsum);
    scanb_kernel<<<1, 128, 0, stream>>>(bsum, boff, rowptr);
    final_kernel<<<SCAN_NBLOCKS, 256, 0, stream>>>(deg, boff, rowptr, cursor);

    fill_kernel<<<(N_EDGES + 255) / 256, 256, 0, stream>>>(src, dst, cursor, csr_src);

    mmfused_kernel<<<(N_NODES + 127) / 128, 256, 0, stream>>>(feat, wp, b_self, b_neigh, out, t);

    gather_kernel<<<25000, 256, 0, stream>>>(t, csr_src, rowptr, out);
}

// Round 10
// 138.156 us; speedup vs baseline: 1.1593x; 1.0706x over previous
//
#include <hip/hip_runtime.h>

// GraphSAGE mean aggregator on MI355X.
// hn = segment_mean(fb[src], dst);  out = fb@W_self + hn@W_neigh + biases
// (fb = bf16(feat); one K=256 MFMA pass; out written exactly once.)
// R2: CSR + gather-side reduction.  R3: parallel scan.  R4: bf16 MFMA.
// R8: gather = branch-free predicated 8-batches.  R9: natural-width CSR build.
// R10: gather BEFORE matmul (writes hn bf16 once — kills the 100MB out-RMW);
//      mmfused = single K=256 pass over [fb|hn]; feat cvt fused into prepass.

constexpr int N_NODES = 100000;
constexpr int N_EDGES = 640000;
constexpr int D = 128;

constexpr int SCAN_ELEMS_PER_BLOCK = 1024;   // 256 threads x 4
constexpr int SCAN_NBLOCKS = (N_NODES + SCAN_ELEMS_PER_BLOCK - 1) / SCAN_ELEMS_PER_BLOCK; // 98

typedef __attribute__((ext_vector_type(8))) short bf16x8;
typedef __attribute__((ext_vector_type(4))) float f32x4;

__device__ __forceinline__ unsigned short f2bf(float f) {
    unsigned int u = __float_as_uint(f);
    unsigned int r = u + 0x7FFFu + ((u >> 16) & 1u);   // round-to-nearest-even
    return (unsigned short)(r >> 16);
}

// ------- prepass: deg atomics + weight packing + feat->bf16 (independent) -----
// wp flat index i = (((m*4+ks)*4+h)*128 + c)*8 + r  holds  bf16(W_m[ks*32+h*8+r][c])
// Same (h,r)->k map as the A-fragment build in mmfused (shared k-permutation).
__global__ void prepass_kernel(const int* __restrict__ dst, int* __restrict__ deg,
                               const float* __restrict__ Ws, const float* __restrict__ Wn,
                               unsigned short* __restrict__ wp,
                               const float* __restrict__ feat, unsigned short* __restrict__ fb) {
    const int gid = blockIdx.x * blockDim.x + threadIdx.x;   // 640K threads
    if (gid < N_EDGES) atomicAdd(&deg[dst[gid]], 1);
    if (gid < 2 * D * D) {
        int i = gid;
        int r  = i & 7;
        int c  = (i >> 3) & 127;
        int h  = (i >> 10) & 3;
        int ks = (i >> 12) & 3;
        int m  = i >> 14;
        const float* W = m ? Wn : Ws;
        int k = ks * 32 + h * 8 + r;
        wp[i] = f2bf(W[k * D + c]);
    }
    // feat -> fb, grid-stride over 3.2M float4 items
    const int total4 = N_NODES * D / 4;
    for (int i = gid; i < total4; i += N_EDGES) {
        float4 v = ((const float4*)feat)[i];
        ushort4 o;
        o.x = f2bf(v.x); o.y = f2bf(v.y); o.z = f2bf(v.z); o.w = f2bf(v.w);
        ((ushort4*)fb)[i] = o;
    }
}

// ---------------- 3-phase scan + fill (natural widths) ----------------

__global__ __launch_bounds__(256) void partial_kernel(const int* __restrict__ deg,
                                                      int* __restrict__ bsum) {
    __shared__ int wsum[4];
    const int tid = threadIdx.x;
    const int base = (blockIdx.x * 256 + tid) * 4;
    int s = 0;
    #pragma unroll
    for (int j = 0; j < 4; j++) {
        int idx = base + j;
        if (idx < N_NODES) s += deg[idx];
    }
    for (int off = 32; off > 0; off >>= 1) s += __shfl_down(s, off, 64);
    if ((tid & 63) == 0) wsum[tid >> 6] = s;
    __syncthreads();
    if (tid == 0) bsum[blockIdx.x] = wsum[0] + wsum[1] + wsum[2] + wsum[3];
}

__global__ __launch_bounds__(128) void scanb_kernel(const int* __restrict__ bsum,
                                                    int* __restrict__ boff,
                                                    int* __restrict__ rowptr) {
    __shared__ int s[128];
    const int tid = threadIdx.x;
    int v = (tid < SCAN_NBLOCKS) ? bsum[tid] : 0;
    s[tid] = v;
    __syncthreads();
    for (int off = 1; off < 128; off <<= 1) {
        int u = (tid >= off) ? s[tid - off] : 0;
        __syncthreads();
        s[tid] += u;
        __syncthreads();
    }
    if (tid < SCAN_NBLOCKS) boff[tid] = s[tid] - v;
    if (tid == 0) rowptr[N_NODES] = N_EDGES;
}

__global__ __launch_bounds__(256) void final_kernel(const int* __restrict__ deg,
                                                    const int* __restrict__ boff,
                                                    int* __restrict__ rowptr,
                                                    int* __restrict__ cursor) {
    __shared__ int wsum[4];
    const int tid = threadIdx.x;
    const int lane = tid & 63;
    const int wave = tid >> 6;
    const int base = (blockIdx.x * 256 + tid) * 4;

    int local[4];
    int tsum = 0;
    #pragma unroll
    for (int j = 0; j < 4; j++) {
        int idx = base + j;
        local[j] = (idx < N_NODES) ? deg[idx] : 0;
        tsum += local[j];
    }
    int incl = tsum;
    for (int off = 1; off < 64; off <<= 1) {
        int u = __shfl_up(incl, off, 64);
        if (lane >= off) incl += u;
    }
    if (lane == 63) wsum[wave] = incl;
    __syncthreads();
    int woff = 0;
    for (int w = 0; w < 4; w++) woff += (w < wave) ? wsum[w] : 0;

    int run = boff[blockIdx.x] + woff + (incl - tsum);
    #pragma unroll
    for (int j = 0; j < 4; j++) {
        int idx = base + j;
        if (idx < N_NODES) {
            rowptr[idx] = run;
            cursor[idx] = run;
            run += local[j];
        }
    }
}

__global__ void fill_kernel(const int* __restrict__ src, const int* __restrict__ dst,
                            int* __restrict__ cursor, int* __restrict__ csr_src) {
    int e = blockIdx.x * blockDim.x + threadIdx.x;
    if (e < N_EDGES) {
        int pos = atomicAdd(&cursor[dst[e]], 1);
        csr_src[pos] = src[e];
    }
}

// ---------------- gather: mean(fb[src]) -> hn (bf16, written once) -----------
// One wave per node; branch-free predicated 8-batches; lane packs 2 bf16.
__global__ __launch_bounds__(256) void gather_kernel(
    const unsigned short* __restrict__ fb, const int* __restrict__ csr_src,
    const int* __restrict__ rowptr, unsigned short* __restrict__ hn)
{
    const int lane = threadIdx.x & 63;
    const int n = (blockIdx.x * blockDim.x + threadIdx.x) >> 6;
    if (n >= N_NODES) return;

    const int e0 = rowptr[n];
    const int e1 = rowptr[n + 1];

    float ax = 0.f, ay = 0.f;
    for (int base = e0; base < e1; base += 8) {
        int sidx[8];
        #pragma unroll
        for (int j = 0; j < 8; j++) {
            int ee = base + j;
            ee = (ee < e1) ? ee : (e1 - 1);          // clamp, no branch
            sidx[j] = csr_src[ee];
        }
        unsigned int v[8];
        #pragma unroll
        for (int j = 0; j < 8; j++)
            v[j] = ((const unsigned int*)(fb + (size_t)sidx[j] * D))[lane];
        #pragma unroll
        for (int j = 0; j < 8; j++) {
            const float w = (base + j < e1) ? 1.0f : 0.0f;
            ax = fmaf(w, __uint_as_float(v[j] << 16), ax);
            ay = fmaf(w, __uint_as_float(v[j] & 0xFFFF0000u), ay);
        }
    }
    const float sc = 1.0f / (float)max(e1 - e0, 1);
    const unsigned int packed =
        ((unsigned int)f2bf(ay * sc) << 16) | (unsigned int)f2bf(ax * sc);
    ((unsigned int*)(hn + (size_t)n * D))[lane] = packed;   // zero-deg -> 0
}

// ---------------- single K=256 matmul: out = fb@Ws + hn@Wn + bias ------------
// Block = 256 thr = 4 waves; wave owns 2 row-tiles of 16 -> block = 128 rows.
__global__ __launch_bounds__(256) void mmfused_kernel(
    const unsigned short* __restrict__ fb, const unsigned short* __restrict__ hn,
    const unsigned short* __restrict__ wp,
    const float* __restrict__ b_self, const float* __restrict__ b_neigh,
    float* __restrict__ out)
{
    __shared__ unsigned short lw[2 * 4 * 4 * 128 * 8];   // 64 KB packed fragments

    const int tid = threadIdx.x;
    {
        const uint4* s = (const uint4*)wp;
        uint4* d = (uint4*)lw;
        #pragma unroll
        for (int i = 0; i < 16; i++) d[tid + i * 256] = s[tid + i * 256];
    }
    __syncthreads();

    const int wave = tid >> 6, lane = tid & 63;
    const int h = lane >> 4, c = lane & 15;
    const int row_base = blockIdx.x * 128 + wave * 32;

    // A fragments: a[m][ti][ks], m=0 -> fb, m=1 -> hn (both bf16 row-major).
    bf16x8 a[2][2][4];
    #pragma unroll
    for (int ti = 0; ti < 2; ti++) {
        int row = row_base + ti * 16 + c;
        int rowc = min(row, N_NODES - 1);             // clamp; stores are guarded
        const bf16x8* f0 = (const bf16x8*)(fb + (size_t)rowc * D);
        const bf16x8* f1 = (const bf16x8*)(hn + (size_t)rowc * D);
        #pragma unroll
        for (int ks = 0; ks < 4; ks++) {
            a[0][ti][ks] = f0[ks * 4 + h];
            a[1][ti][ks] = f1[ks * 4 + h];
        }
    }

    for (int ct = 0; ct < 8; ct++) {
        f32x4 acc[2];
        #pragma unroll
        for (int ti = 0; ti < 2; ti++) acc[ti] = f32x4{0.f, 0.f, 0.f, 0.f};

        #pragma unroll
        for (int m = 0; m < 2; m++) {
            bf16x8 b[4];
            #pragma unroll
            for (int ks = 0; ks < 4; ks++)
                b[ks] = ((const bf16x8*)lw)[((m * 4 + ks) * 4 + h) * 128 + ct * 16 + c];
            #pragma unroll
            for (int ks = 0; ks < 4; ks++)
                #pragma unroll
                for (int ti = 0; ti < 2; ti++)
                    acc[ti] = __builtin_amdgcn_mfma_f32_16x16x32_bf16(a[m][ti][ks], b[ks], acc[ti], 0, 0, 0);
        }

        const int col = ct * 16 + c;
        const float bias = b_self[col] + b_neigh[col];
        #pragma unroll
        for (int ti = 0; ti < 2; ti++) {
            if (row_base + ti * 16 < N_NODES) {       // N%16==0: tile guard exact
                #pragma unroll
                for (int q = 0; q < 4; q++) {
                    int row = row_base + ti * 16 + h * 4 + q;   // C/D: row=(lane>>4)*4+reg
                    out[(size_t)row * D + col] = acc[ti][q] + bias;
                }
            }
        }
    }
}

extern "C" void kernel_launch(void* const* d_in, const int* in_sizes, int n_in,
                              void* d_out, int out_size, void* d_ws, size_t ws_size,
                              hipStream_t stream) {
    const float* feat    = (const float*)d_in[0];
    const int*   src     = (const int*)d_in[1];
    const int*   dst     = (const int*)d_in[2];
    const float* W_self  = (const float*)d_in[3];
    const float* b_self  = (const float*)d_in[4];
    const float* W_neigh = (const float*)d_in[5];
    const float* b_neigh = (const float*)d_in[6];
    float* out = (float*)d_out;

    // ws layout: fb [N*D bf16] | hn [N*D bf16] | wp [2*D*D bf16] | deg [N] |
    //            rowptr [N+1] | cursor [N] | csr_src [E] | bsum [98] | boff [98]
    unsigned short* fb = (unsigned short*)d_ws;
    unsigned short* hn = fb + (size_t)N_NODES * D;
    unsigned short* wp = hn + (size_t)N_NODES * D;
    int*   deg     = (int*)(wp + 2 * D * D);
    int*   rowptr  = deg + N_NODES;
    int*   cursor  = rowptr + (N_NODES + 1);
    int*   csr_src = cursor + N_NODES;
    int*   bsum    = csr_src + N_EDGES;
    int*   boff    = bsum + SCAN_NBLOCKS;

    (void)hipMemsetAsync(deg, 0, N_NODES * sizeof(int), stream);

    prepass_kernel<<<(N_EDGES + 255) / 256, 256, 0, stream>>>(dst, deg, W_self, W_neigh,
                                                              wp, feat, fb);

    partial_kernel<<<SCAN_NBLOCKS, 256, 0, stream>>>(deg, bsum);
    scanb_kernel<<<1, 128, 0, stream>>>(bsum, boff, rowptr);
    final_kernel<<<SCAN_NBLOCKS, 256, 0, stream>>>(deg, boff, rowptr, cursor);

    fill_kernel<<<(N_EDGES + 255) / 256, 256, 0, stream>>>(src, dst, cursor, csr_src);

    gather_kernel<<<25000, 256, 0, stream>>>(fb, csr_src, rowptr, hn);

    mmfused_kernel<<<(N_NODES + 127) / 128, 256, 0, stream>>>(fb, hn, wp, b_self, b_neigh, out);
}

// Round 11
// 137.297 us; speedup vs baseline: 1.1665x; 1.0063x over previous
//
#include <hip/hip_runtime.h>

// GraphSAGE mean aggregator on MI355X.
// hn = segment_mean(fb[src], dst);  out = fb@W_self + hn@W_neigh + biases
// (fb = bf16(feat); one K=256 MFMA pass; out written exactly once.)
// R2: CSR + gather-side reduction.  R3: parallel scan.  R4: bf16 MFMA.
// R8: gather = branch-free predicated 8-batches.  R9: natural-width CSR build.
// R10: gather before matmul (hn bf16 written once); K=256 single mm pass.
// R11: hipMemsetAsync(deg) -> own zero kernel. rocclr fillBuffer ran at
//      10 GB/s / 39.5us for 400KB (tiny fixed grid); ours is ~2-3us.

constexpr int N_NODES = 100000;
constexpr int N_EDGES = 640000;
constexpr int D = 128;

constexpr int SCAN_ELEMS_PER_BLOCK = 1024;   // 256 threads x 4
constexpr int SCAN_NBLOCKS = (N_NODES + SCAN_ELEMS_PER_BLOCK - 1) / SCAN_ELEMS_PER_BLOCK; // 98

typedef __attribute__((ext_vector_type(8))) short bf16x8;
typedef __attribute__((ext_vector_type(4))) float f32x4;

__device__ __forceinline__ unsigned short f2bf(float f) {
    unsigned int u = __float_as_uint(f);
    unsigned int r = u + 0x7FFFu + ((u >> 16) & 1u);   // round-to-nearest-even
    return (unsigned short)(r >> 16);
}

// ---------------- zero deg (int4-wide, full-width grid) ----------------
__global__ __launch_bounds__(256) void zero_deg_kernel(int4* __restrict__ deg4) {
    int i = blockIdx.x * 256 + threadIdx.x;
    if (i < N_NODES / 4) deg4[i] = int4{0, 0, 0, 0};
}

// ------- prepass: deg atomics + weight packing + feat->bf16 (independent) -----
// wp flat index i = (((m*4+ks)*4+h)*128 + c)*8 + r  holds  bf16(W_m[ks*32+h*8+r][c])
// Same (h,r)->k map as the A-fragment build in mmfused (shared k-permutation).
__global__ void prepass_kernel(const int* __restrict__ dst, int* __restrict__ deg,
                               const float* __restrict__ Ws, const float* __restrict__ Wn,
                               unsigned short* __restrict__ wp,
                               const float* __restrict__ feat, unsigned short* __restrict__ fb) {
    const int gid = blockIdx.x * blockDim.x + threadIdx.x;   // 640K threads
    if (gid < N_EDGES) atomicAdd(&deg[dst[gid]], 1);
    if (gid < 2 * D * D) {
        int i = gid;
        int r  = i & 7;
        int c  = (i >> 3) & 127;
        int h  = (i >> 10) & 3;
        int ks = (i >> 12) & 3;
        int m  = i >> 14;
        const float* W = m ? Wn : Ws;
        int k = ks * 32 + h * 8 + r;
        wp[i] = f2bf(W[k * D + c]);
    }
    // feat -> fb, grid-stride over 3.2M float4 items
    const int total4 = N_NODES * D / 4;
    for (int i = gid; i < total4; i += N_EDGES) {
        float4 v = ((const float4*)feat)[i];
        ushort4 o;
        o.x = f2bf(v.x); o.y = f2bf(v.y); o.z = f2bf(v.z); o.w = f2bf(v.w);
        ((ushort4*)fb)[i] = o;
    }
}

// ---------------- 3-phase scan + fill (natural widths) ----------------

__global__ __launch_bounds__(256) void partial_kernel(const int* __restrict__ deg,
                                                      int* __restrict__ bsum) {
    __shared__ int wsum[4];
    const int tid = threadIdx.x;
    const int base = (blockIdx.x * 256 + tid) * 4;
    int s = 0;
    #pragma unroll
    for (int j = 0; j < 4; j++) {
        int idx = base + j;
        if (idx < N_NODES) s += deg[idx];
    }
    for (int off = 32; off > 0; off >>= 1) s += __shfl_down(s, off, 64);
    if ((tid & 63) == 0) wsum[tid >> 6] = s;
    __syncthreads();
    if (tid == 0) bsum[blockIdx.x] = wsum[0] + wsum[1] + wsum[2] + wsum[3];
}

__global__ __launch_bounds__(128) void scanb_kernel(const int* __restrict__ bsum,
                                                    int* __restrict__ boff,
                                                    int* __restrict__ rowptr) {
    __shared__ int s[128];
    const int tid = threadIdx.x;
    int v = (tid < SCAN_NBLOCKS) ? bsum[tid] : 0;
    s[tid] = v;
    __syncthreads();
    for (int off = 1; off < 128; off <<= 1) {
        int u = (tid >= off) ? s[tid - off] : 0;
        __syncthreads();
        s[tid] += u;
        __syncthreads();
    }
    if (tid < SCAN_NBLOCKS) boff[tid] = s[tid] - v;
    if (tid == 0) rowptr[N_NODES] = N_EDGES;
}

__global__ __launch_bounds__(256) void final_kernel(const int* __restrict__ deg,
                                                    const int* __restrict__ boff,
                                                    int* __restrict__ rowptr,
                                                    int* __restrict__ cursor) {
    __shared__ int wsum[4];
    const int tid = threadIdx.x;
    const int lane = tid & 63;
    const int wave = tid >> 6;
    const int base = (blockIdx.x * 256 + tid) * 4;

    int local[4];
    int tsum = 0;
    #pragma unroll
    for (int j = 0; j < 4; j++) {
        int idx = base + j;
        local[j] = (idx < N_NODES) ? deg[idx] : 0;
        tsum += local[j];
    }
    int incl = tsum;
    for (int off = 1; off < 64; off <<= 1) {
        int u = __shfl_up(incl, off, 64);
        if (lane >= off) incl += u;
    }
    if (lane == 63) wsum[wave] = incl;
    __syncthreads();
    int woff = 0;
    for (int w = 0; w < 4; w++) woff += (w < wave) ? wsum[w] : 0;

    int run = boff[blockIdx.x] + woff + (incl - tsum);
    #pragma unroll
    for (int j = 0; j < 4; j++) {
        int idx = base + j;
        if (idx < N_NODES) {
            rowptr[idx] = run;
            cursor[idx] = run;
            run += local[j];
        }
    }
}

__global__ void fill_kernel(const int* __restrict__ src, const int* __restrict__ dst,
                            int* __restrict__ cursor, int* __restrict__ csr_src) {
    int e = blockIdx.x * blockDim.x + threadIdx.x;
    if (e < N_EDGES) {
        int pos = atomicAdd(&cursor[dst[e]], 1);
        csr_src[pos] = src[e];
    }
}

// ---------------- gather: mean(fb[src]) -> hn (bf16, written once) -----------
// One wave per node; branch-free predicated 8-batches; lane packs 2 bf16.
__global__ __launch_bounds__(256) void gather_kernel(
    const unsigned short* __restrict__ fb, const int* __restrict__ csr_src,
    const int* __restrict__ rowptr, unsigned short* __restrict__ hn)
{
    const int lane = threadIdx.x & 63;
    const int n = (blockIdx.x * blockDim.x + threadIdx.x) >> 6;
    if (n >= N_NODES) return;

    const int e0 = rowptr[n];
    const int e1 = rowptr[n + 1];

    float ax = 0.f, ay = 0.f;
    for (int base = e0; base < e1; base += 8) {
        int sidx[8];
        #pragma unroll
        for (int j = 0; j < 8; j++) {
            int ee = base + j;
            ee = (ee < e1) ? ee : (e1 - 1);          // clamp, no branch
            sidx[j] = csr_src[ee];
        }
        unsigned int v[8];
        #pragma unroll
        for (int j = 0; j < 8; j++)
            v[j] = ((const unsigned int*)(fb + (size_t)sidx[j] * D))[lane];
        #pragma unroll
        for (int j = 0; j < 8; j++) {
            const float w = (base + j < e1) ? 1.0f : 0.0f;
            ax = fmaf(w, __uint_as_float(v[j] << 16), ax);
            ay = fmaf(w, __uint_as_float(v[j] & 0xFFFF0000u), ay);
        }
    }
    const float sc = 1.0f / (float)max(e1 - e0, 1);
    const unsigned int packed =
        ((unsigned int)f2bf(ay * sc) << 16) | (unsigned int)f2bf(ax * sc);
    ((unsigned int*)(hn + (size_t)n * D))[lane] = packed;   // zero-deg -> 0
}

// ---------------- single K=256 matmul: out = fb@Ws + hn@Wn + bias ------------
// Block = 256 thr = 4 waves; wave owns 2 row-tiles of 16 -> block = 128 rows.
__global__ __launch_bounds__(256) void mmfused_kernel(
    const unsigned short* __restrict__ fb, const unsigned short* __restrict__ hn,
    const unsigned short* __restrict__ wp,
    const float* __restrict__ b_self, const float* __restrict__ b_neigh,
    float* __restrict__ out)
{
    __shared__ unsigned short lw[2 * 4 * 4 * 128 * 8];   // 64 KB packed fragments

    const int tid = threadIdx.x;
    {
        const uint4* s = (const uint4*)wp;
        uint4* d = (uint4*)lw;
        #pragma unroll
        for (int i = 0; i < 16; i++) d[tid + i * 256] = s[tid + i * 256];
    }
    __syncthreads();

    const int wave = tid >> 6, lane = tid & 63;
    const int h = lane >> 4, c = lane & 15;
    const int row_base = blockIdx.x * 128 + wave * 32;

    // A fragments: a[m][ti][ks], m=0 -> fb, m=1 -> hn (both bf16 row-major).
    bf16x8 a[2][2][4];
    #pragma unroll
    for (int ti = 0; ti < 2; ti++) {
        int row = row_base + ti * 16 + c;
        int rowc = min(row, N_NODES - 1);             // clamp; stores are guarded
        const bf16x8* f0 = (const bf16x8*)(fb + (size_t)rowc * D);
        const bf16x8* f1 = (const bf16x8*)(hn + (size_t)rowc * D);
        #pragma unroll
        for (int ks = 0; ks < 4; ks++) {
            a[0][ti][ks] = f0[ks * 4 + h];
            a[1][ti][ks] = f1[ks * 4 + h];
        }
    }

    for (int ct = 0; ct < 8; ct++) {
        f32x4 acc[2];
        #pragma unroll
        for (int ti = 0; ti < 2; ti++) acc[ti] = f32x4{0.f, 0.f, 0.f, 0.f};

        #pragma unroll
        for (int m = 0; m < 2; m++) {
            bf16x8 b[4];
            #pragma unroll
            for (int ks = 0; ks < 4; ks++)
                b[ks] = ((const bf16x8*)lw)[((m * 4 + ks) * 4 + h) * 128 + ct * 16 + c];
            #pragma unroll
            for (int ks = 0; ks < 4; ks++)
                #pragma unroll
                for (int ti = 0; ti < 2; ti++)
                    acc[ti] = __builtin_amdgcn_mfma_f32_16x16x32_bf16(a[m][ti][ks], b[ks], acc[ti], 0, 0, 0);
        }

        const int col = ct * 16 + c;
        const float bias = b_self[col] + b_neigh[col];
        #pragma unroll
        for (int ti = 0; ti < 2; ti++) {
            if (row_base + ti * 16 < N_NODES) {       // N%16==0: tile guard exact
                #pragma unroll
                for (int q = 0; q < 4; q++) {
                    int row = row_base + ti * 16 + h * 4 + q;   // C/D: row=(lane>>4)*4+reg
                    out[(size_t)row * D + col] = acc[ti][q] + bias;
                }
            }
        }
    }
}

extern "C" void kernel_launch(void* const* d_in, const int* in_sizes, int n_in,
                              void* d_out, int out_size, void* d_ws, size_t ws_size,
                              hipStream_t stream) {
    const float* feat    = (const float*)d_in[0];
    const int*   src     = (const int*)d_in[1];
    const int*   dst     = (const int*)d_in[2];
    const float* W_self  = (const float*)d_in[3];
    const float* b_self  = (const float*)d_in[4];
    const float* W_neigh = (const float*)d_in[5];
    const float* b_neigh = (const float*)d_in[6];
    float* out = (float*)d_out;

    // ws layout: fb [N*D bf16] | hn [N*D bf16] | wp [2*D*D bf16] | deg [N] |
    //            rowptr [N+1] | cursor [N] | csr_src [E] | bsum [98] | boff [98]
    unsigned short* fb = (unsigned short*)d_ws;
    unsigned short* hn = fb + (size_t)N_NODES * D;
    unsigned short* wp = hn + (size_t)N_NODES * D;
    int*   deg     = (int*)(wp + 2 * D * D);
    int*   rowptr  = deg + N_NODES;
    int*   cursor  = rowptr + (N_NODES + 1);
    int*   csr_src = cursor + N_NODES;
    int*   bsum    = csr_src + N_EDGES;
    int*   boff    = bsum + SCAN_NBLOCKS;

    zero_deg_kernel<<<(N_NODES / 4 + 255) / 256, 256, 0, stream>>>((int4*)deg);

    prepass_kernel<<<(N_EDGES + 255) / 256, 256, 0, stream>>>(dst, deg, W_self, W_neigh,
                                                              wp, feat, fb);

    partial_kernel<<<SCAN_NBLOCKS, 256, 0, stream>>>(deg, bsum);
    scanb_kernel<<<1, 128, 0, stream>>>(bsum, boff, rowptr);
    final_kernel<<<SCAN_NBLOCKS, 256, 0, stream>>>(deg, boff, rowptr, cursor);

    fill_kernel<<<(N_EDGES + 255) / 256, 256, 0, stream>>>(src, dst, cursor, csr_src);

    gather_kernel<<<25000, 256, 0, stream>>>(fb, csr_src, rowptr, hn);

    mmfused_kernel<<<(N_NODES + 127) / 128, 256, 0, stream>>>(fb, hn, wp, b_self, b_neigh, out);
}